// Round 4
// baseline (186.270 us; speedup 1.0000x reference)
//
#include <hip/hip_runtime.h>
#include <math.h>

typedef __bf16 bf16x8 __attribute__((ext_vector_type(8)));
typedef float f32x4 __attribute__((ext_vector_type(4)));
typedef short short4v __attribute__((ext_vector_type(4)));

#define NB 4
#define NT 48
#define NV 32
#define ND 512
#define NH 8
#define NN 1536   // T*V
#define NBN 6144  // B*N
#define L2E 1.44269504f

#define GLOAD_LDS(g, l) \
    __builtin_amdgcn_global_load_lds( \
        (const __attribute__((address_space(1))) void*)(g), \
        (__attribute__((address_space(3))) void*)(l), 16, 0, 0)

// ---------------------------------------------------------------------------
// prep: fused conv_h (blocks 0..1535) + weight transpose (1536..1791) +
// kx2 obs/zero fragment segments (1792..2175).  log2e folded into Wq/bq.
// kx2 layout (frag-major, attn wave-private):
//   frag(bh, mt, w, ks) of 512 elems; lane (quad,l16) holds 8 elems at
//   quad*128 + l16*8;  k = ks*32 + quad*8 + j.  ks=2: k 64..79 = oq, 80..95 = 0.
// ---------------------------------------------------------------------------
__global__ __launch_bounds__(256) void prep(
    const float* __restrict__ h, const float* __restrict__ obs,
    const float* __restrict__ Wq, const float* __restrict__ Wk,
    const float* __restrict__ Wv, const float* __restrict__ Wo,
    const float* __restrict__ bq, const float* __restrict__ bk,
    const float* __restrict__ bv,
    const float* __restrict__ Wok, const float* __restrict__ bok,
    __bf16* __restrict__ h_bf, __bf16* __restrict__ WcatT,
    __bf16* __restrict__ WoT, float* __restrict__ biascat,
    __bf16* __restrict__ kx)
{
    __shared__ float ts[64][68];
    const int tid = threadIdx.x;
    const int bx = blockIdx.x;
    if (bx < 1536) {
        int t = bx * 256 + tid;
        const float4* src = (const float4*)h + (size_t)t * 2;
        float4 a = src[0], b = src[1];
        __bf16 r[8] = {(__bf16)a.x, (__bf16)a.y, (__bf16)a.z, (__bf16)a.w,
                       (__bf16)b.x, (__bf16)b.y, (__bf16)b.z, (__bf16)b.w};
        *(uint4*)(h_bf + (size_t)t * 8) = *(uint4*)r;
    } else if (bx < 1792) {
        int bw = bx - 1536;
        const int p = bw >> 6, tile = bw & 63;
        const int k0 = (tile >> 3) * 64, c0 = (tile & 7) * 64;
        const float* W = (p == 0) ? Wq : (p == 1) ? Wk : (p == 2) ? Wv : Wo;
        const float scale = (p == 0) ? 0.125f * L2E : 1.0f;
        #pragma unroll
        for (int i = 0; i < 4; i++) {
            int r = (tid >> 4) + i * 16;
            float4 v = *(const float4*)(W + (size_t)(k0 + r) * 512 + c0 + (tid & 15) * 4);
            *(float4*)&ts[r][(tid & 15) * 4] = v;
        }
        __syncthreads();
        __bf16 tmp[16];
        #pragma unroll
        for (int j = 0; j < 16; j++)
            tmp[j] = (__bf16)(ts[(tid & 3) * 16 + j][tid >> 2] * scale);
        int crow = c0 + (tid >> 2);
        __bf16* dst = (p < 3)
            ? WcatT + ((size_t)(p * 512 + crow)) * 512 + k0 + (tid & 3) * 16
            : WoT   + ((size_t)crow) * 512 + k0 + (tid & 3) * 16;
        *(uint4*)dst = *(uint4*)tmp;
        *(uint4*)(dst + 8) = *(uint4*)(tmp + 8);
        if (p < 3 && k0 == 0 && tid < 64) {
            const float* bb = (p == 0) ? bq : (p == 1) ? bk : bv;
            biascat[p * 512 + c0 + tid] = bb[c0 + tid] * scale;
        }
    } else {
        int t = (bx - 1792) * 256 + tid;               // 0..98303
        int row = t >> 1, half = t & 1;                // row = bh*1536 + n
        int bh = row / NN, n = row - bh * NN;
        int mt = n >> 6, wv = (n >> 4) & 3, l16k = n & 15;
        __bf16* dst = kx + (((size_t)(bh * 24 + mt) * 4 + wv) * 3 + 2) * 512
                         + (half * 2) * 128 + l16k * 8;
        if (half == 0) {
            int hh = bh & 7;
            int b = bh >> 3;
            size_t bn = (size_t)b * NN + n;
            float o0 = obs[bn * 2], o1 = obs[bn * 2 + 1];
            int f = hh * 16;
            __bf16 tmp[16];
            #pragma unroll
            for (int j = 0; j < 16; j++)
                tmp[j] = (__bf16)(o0 * Wok[f + j] + o1 * Wok[128 + f + j] + bok[f + j]);
            *(uint4*)dst         = *(uint4*)tmp;
            *(uint4*)(dst + 128) = *(uint4*)(tmp + 8);
        } else {
            uint4 z = {0, 0, 0, 0};
            *(uint4*)dst         = z;
            *(uint4*)(dst + 128) = z;
        }
    }
}

// ---------------------------------------------------------------------------
// bf16 MFMA GEMM — software-pipelined (kept from R1, measured win).
// K-tile epilogue -> kx2 fragment layout (ks = d>>5, quad = (d>>3)&3, j=d&7).
// V-tile epilogue -> vt3 fragment layout for 16x16x16 PV A-frags:
//   frag(bh, mt, w, dt) of 256 elems; lane (quad,l16) holds 4 elems at
//   lane*4;  d = dt*16 + l16, m_local = quad*4 + jj.
// ---------------------------------------------------------------------------
template<int TM, bool BF16OUT>
__global__ __launch_bounds__(256) void gemm_mfma(
    const __bf16* __restrict__ A, const __bf16* __restrict__ Bt,
    const float* __restrict__ bias, float* __restrict__ Cf,
    __bf16* __restrict__ qarr, __bf16* __restrict__ kx,
    __bf16* __restrict__ vt)
{
    constexpr int MT = TM / 32;
    __shared__ __align__(16) char smem[34816];
    char* const As0 = smem;
    char* const As1 = smem + TM * 64;
    char* const Bs0 = smem + TM * 128;
    char* const Bs1 = smem + TM * 128 + 8192;
    const int tid = threadIdx.x;
    const int w = tid >> 6, lane = tid & 63;
    const int quad = lane >> 4, l16 = lane & 15;
    const int wm = w >> 1, wn = w & 1;
    const int n0 = blockIdx.x * 128, m0 = blockIdx.y * TM;

    const int sm = tid >> 2;
    const int sk = ((tid & 3) ^ ((sm >> 1) & 3)) * 8;
    const __bf16* aptr = A  + (size_t)(m0 + sm) * 512 + sk;
    const __bf16* bptr = Bt + (size_t)(n0 + sm) * 512 + sk;

    f32x4 zero4 = {0.f, 0.f, 0.f, 0.f};
    f32x4 acc[MT][4];
    #pragma unroll
    for (int i = 0; i < MT; i++)
        #pragma unroll
        for (int j = 0; j < 4; j++) acc[i][j] = zero4;

    auto STAGE = [&](char* dA, char* dB, int kt) {
        GLOAD_LDS(aptr + kt, dA + tid * 16);
        if (TM == 128) GLOAD_LDS(aptr + 64 * 512 + kt, dA + 4096 + tid * 16);
        GLOAD_LDS(bptr + kt, dB + tid * 16);
        GLOAD_LDS(bptr + 64 * 512 + kt, dB + 4096 + tid * 16);
    };
    auto COMPUTE = [&](const char* Asb, const char* Bsb) {
        bf16x8 af[MT], bfr[4];
        #pragma unroll
        for (int mt = 0; mt < MT; mt++) {
            int rr = wm * (TM / 2) + mt * 16 + l16;
            af[mt] = *(const bf16x8*)(Asb + rr * 64 + (quad ^ ((rr >> 1) & 3)) * 16);
        }
        #pragma unroll
        for (int nt = 0; nt < 4; nt++) {
            int rr = wn * 64 + nt * 16 + l16;
            bfr[nt] = *(const bf16x8*)(Bsb + rr * 64 + (quad ^ ((rr >> 1) & 3)) * 16);
        }
        #pragma unroll
        for (int mt = 0; mt < MT; mt++)
            #pragma unroll
            for (int nt = 0; nt < 4; nt++)
                acc[mt][nt] = __builtin_amdgcn_mfma_f32_16x16x32_bf16(
                    af[mt], bfr[nt], acc[mt][nt], 0, 0, 0);
    };

    STAGE(As0, Bs0, 0);
    asm volatile("s_waitcnt vmcnt(0)" ::: "memory");
    __builtin_amdgcn_s_barrier();
    for (int kt = 0; kt < 512; kt += 64) {
        STAGE(As1, Bs1, kt + 32);          // always valid: last is kt=448 -> 480
        COMPUTE(As0, Bs0);
        asm volatile("s_waitcnt vmcnt(0)" ::: "memory");
        __builtin_amdgcn_s_barrier();
        if (kt + 64 < 512) STAGE(As0, Bs0, kt + 64);
        COMPUTE(As1, Bs1);
        asm volatile("s_waitcnt vmcnt(0)" ::: "memory");
        __builtin_amdgcn_s_barrier();
    }

    __syncthreads();   // frag reads done; smem becomes C-stage
    if (BF16OUT) {
        if (n0 >= 1024) {
            // ---- V tile: stage TRANSPOSED (CsT[col][136 rows]), write vt3 ----
            __bf16* CsT = (__bf16*)smem;
            #pragma unroll
            for (int nt = 0; nt < 4; nt++) {
                int cl = wn * 64 + nt * 16 + l16;
                float bia = bias[n0 + cl];
                #pragma unroll
                for (int mt = 0; mt < MT; mt++) {
                    int rl0 = wm * (TM / 2) + mt * 16 + quad * 4;
                    __bf16 pk[4];
                    #pragma unroll
                    for (int r = 0; r < 4; r++)
                        pk[r] = (__bf16)(acc[mt][nt][r] + bia);
                    *(uint2*)&CsT[cl * 136 + rl0] = *(uint2*)pk;
                }
            }
            __syncthreads();
            int cl = tid >> 1, half = tid & 1;
            int f0 = (n0 + cl) & 511;
            int hh = f0 >> 6, d = f0 & 63;
            int dt = d >> 4, l16v = d & 15;
            int bidx = m0 / NN, nm = m0 - bidx * NN;
            int bh = bidx * 8 + hh;
            int mtv = (nm >> 6) + half;
            #pragma unroll
            for (int j = 0; j < 8; j++) {
                uint4 v = *(uint4*)&CsT[cl * 136 + half * 64 + j * 8];
                __bf16* pp = (__bf16*)&v;
                size_t fo = (((size_t)(bh * 24 + mtv) * 4 + (j >> 1)) * 4 + dt) * 256;
                int q0 = (j & 1) * 2;
                *(uint2*)(vt + fo + q0 * 64 + l16v * 4)       = *(uint2*)&pp[0];
                *(uint2*)(vt + fo + (q0 + 1) * 64 + l16v * 4) = *(uint2*)&pp[4];
            }
        } else {
            // ---- Q/K tile: row-major stage, routed stores ----
            __bf16* Cs = (__bf16*)smem;               // [TM][132]
            #pragma unroll
            for (int mt = 0; mt < MT; mt++)
                #pragma unroll
                for (int nt = 0; nt < 4; nt++) {
                    int cl = wn * 64 + nt * 16 + l16;
                    float bia = bias[n0 + cl];
                    #pragma unroll
                    for (int r = 0; r < 4; r++) {
                        int rl = wm * (TM / 2) + mt * 16 + quad * 4 + r;
                        Cs[rl * 132 + cl] = (__bf16)(acc[mt][nt][r] + bia);
                    }
                }
            __syncthreads();
            int rl = tid >> 1, hb = tid & 1;
            int grow = m0 + rl;
            int col0 = n0 + hb * 64;
            int p = col0 >> 9, f0 = col0 & 511, hh = f0 >> 6;
            int bidx = grow / NN, n = grow - bidx * NN;
            if (p == 0) {
                __bf16* dst = qarr + (size_t)grow * 512 + f0;
                #pragma unroll
                for (int j = 0; j < 8; j++) {
                    uint2 lo = *(uint2*)&Cs[rl * 132 + hb * 64 + j * 8];
                    uint2 hi = *(uint2*)&Cs[rl * 132 + hb * 64 + j * 8 + 4];
                    uint4 v = {lo.x, lo.y, hi.x, hi.y};
                    *(uint4*)(dst + j * 8) = v;
                }
            } else {
                int mtk = n >> 6, wv = (n >> 4) & 3, l16k = n & 15;
                size_t fb = ((size_t)((bidx * 8 + hh) * 24 + mtk) * 4 + wv) * 1536;
                #pragma unroll
                for (int j = 0; j < 8; j++) {
                    uint2 lo = *(uint2*)&Cs[rl * 132 + hb * 64 + j * 8];
                    uint2 hi = *(uint2*)&Cs[rl * 132 + hb * 64 + j * 8 + 4];
                    uint4 v = {lo.x, lo.y, hi.x, hi.y};
                    *(uint4*)(kx + fb + (j >> 2) * 512 + (j & 3) * 128 + l16k * 8) = v;
                }
            }
        }
    } else {
        float* Csf = (float*)smem;                // [64][132]
        #pragma unroll
        for (int mt = 0; mt < MT; mt++)
            #pragma unroll
            for (int nt = 0; nt < 4; nt++) {
                int cl = wn * 64 + nt * 16 + l16;
                float bia = bias[n0 + cl];
                #pragma unroll
                for (int r = 0; r < 4; r++) {
                    int rl = wm * (TM / 2) + mt * 16 + quad * 4 + r;
                    Csf[rl * 132 + cl] = acc[mt][nt][r] + bia;
                }
            }
        __syncthreads();
        int rl = tid >> 2, q4 = tid & 3;
        float* dst = Cf + (size_t)(m0 + rl) * 512 + n0 + q4 * 32;
        #pragma unroll
        for (int j = 0; j < 8; j++) {
            uint4 v = *(uint4*)&Csf[rl * 132 + q4 * 32 + j * 4];
            *(uint4*)(dst + j * 4) = v;
        }
    }
}

// ---------------------------------------------------------------------------
// Flash attention, BARRIER-FREE m-split (R4 rewrite).
// Wave w owns K/V rows m = mt*64 + w*16 + {quad*4+r}; K/V fragments are
// wave-private, loaded global->VGPR from kx2/vt3 (disjoint, no duplication,
// L2-resident via bh%8 XCD swizzle).  QK C-layout (m=quad*4+r, n=l16) IS the
// 16x16x16 B-frag layout (k=quad*4+j, col=l16), so P feeds PV by a pure
// per-lane bf16 convert — no Ps LDS, no shuffles.  Zero LDS / zero barriers
// in the 24-tile loop; waves free-run with 1-tile K/V prefetch.  One LDS
// O/lp cross-wave reduction per block at the end (~19 KB LDS total).
// ---------------------------------------------------------------------------
__global__ __launch_bounds__(256) void attn_mfma(
    const __bf16* __restrict__ qarr, const __bf16* __restrict__ kx,
    const __bf16* __restrict__ vt, const float* __restrict__ obs,
    const float* __restrict__ Woq, const float* __restrict__ boq,
    const float* __restrict__ varb, const float* __restrict__ rtb,
    __bf16* __restrict__ aout)
{
    __shared__ float Or[64][68];      // O^T partial sum [n][d], padded
    __shared__ float lps[4][64];      // per-wave lp partials [w][n]
    __shared__ float2 rts2[96];       // (rts[i], rts[i+1]) pairs

    const int tid = threadIdx.x;
    const int w = tid >> 6, lane = tid & 63;
    const int quad = lane >> 4, l16 = lane & 15;
    const int bh = blockIdx.x, qt = blockIdx.y;   // XCD-locality swizzle
    const int b = bh >> 3, h = bh & 7;
    const int n0 = qt * 64;

    if (tid < 95) {
        float a = rtb[h * 95 + tid] * L2E;
        float c = (tid < 94) ? rtb[h * 95 + tid + 1] * L2E : 0.f;
        rts2[tid].x = a;
        rts2[tid].y = c;
    }

    // wave-private K/V fragment bases (lane-linear within each frag)
    const __bf16* kwb = kx + ((size_t)bh * 24 * 4 + w) * 1536 + lane * 8;
    const __bf16* vwb = vt + ((size_t)bh * 24 * 4 + w) * 1024 + lane * 4;

    // Q fragments (B-operand) for all 4 n-chunks: qf[nt][ks]
    bf16x8 qf[4][3];
    #pragma unroll
    for (int nt = 0; nt < 4; nt++) {
        const size_t qrow = (size_t)(b * NN + n0 + nt * 16 + l16);
        qf[nt][0] = *(const bf16x8*)(qarr + qrow * 512 + h * 64 + quad * 8);
        qf[nt][1] = *(const bf16x8*)(qarr + qrow * 512 + h * 64 + 32 + quad * 8);
        uint4 a2u = {0u, 0u, 0u, 0u};
        if (quad < 2) {
            float o0 = obs[qrow * 2], o1 = obs[qrow * 2 + 1];
            int f = h * 16 + quad * 8;
            const float scq = 0.25f * L2E;
            __bf16 tmp[8];
            #pragma unroll
            for (int j = 0; j < 8; j++)
                tmp[j] = (__bf16)(scq * (o0 * Woq[f + j] + o1 * Woq[128 + f + j]
                                         + boq[f + j]));
            a2u = *(uint4*)tmp;
        }
        qf[nt][2] = *(bf16x8*)&a2u;
    }

    // var-bias: n&31 = (nt&1)*16 + l16;  m&31 = (w&1)*16 + quad*4 + r
    const float* vbp = varb + h * 1024 + (w & 1) * 16 + quad * 4;
    f32x4 vvA = *(const f32x4*)(vbp + l16 * 32);
    f32x4 vvB = *(const f32x4*)(vbp + (16 + l16) * 32);
    vvA *= L2E; vvB *= L2E;

    const int rbase = 2 * qt - (w >> 1) + 47;

    f32x4 zero4 = {0.f, 0.f, 0.f, 0.f};
    f32x4 o_p[4][4];                  // [dt][nt]
    #pragma unroll
    for (int i = 0; i < 4; i++)
        #pragma unroll
        for (int j = 0; j < 4; j++) o_p[i][j] = zero4;
    float lp_s[4] = {0.f, 0.f, 0.f, 0.f};

    // prefetch tile 0
    bf16x8 kc[3]; short4v vc[4];
    #pragma unroll
    for (int ks = 0; ks < 3; ks++) kc[ks] = *(const bf16x8*)(kwb + ks * 512);
    #pragma unroll
    for (int dt = 0; dt < 4; dt++) vc[dt] = *(const short4v*)(vwb + dt * 256);

    __syncthreads();                  // rts2 visible to all waves

    for (int mt = 0; mt < 24; mt++) {
        // prefetch next tile (K and V) — consumed next iteration
        bf16x8 kn[3]; short4v vn[4];
        if (mt + 1 < 24) {
            const __bf16* kp = kwb + (size_t)(mt + 1) * 6144;
            const __bf16* vp = vwb + (size_t)(mt + 1) * 4096;
            #pragma unroll
            for (int ks = 0; ks < 3; ks++) kn[ks] = *(const bf16x8*)(kp + ks * 512);
            #pragma unroll
            for (int dt = 0; dt < 4; dt++) vn[dt] = *(const short4v*)(vp + dt * 256);
        }

        // ---- S^T = K.Q^T over K=96:  sc[nt], m = quad*4+r, n = nt*16+l16 ----
        f32x4 sc[4];
        __builtin_amdgcn_s_setprio(1);
        #pragma unroll
        for (int nt = 0; nt < 4; nt++) {
            f32x4 d = zero4;
            #pragma unroll
            for (int ks = 0; ks < 3; ks++)
                d = __builtin_amdgcn_mfma_f32_16x16x32_bf16(kc[ks], qf[nt][ks], d, 0, 0, 0);
            sc[nt] = d;
        }
        __builtin_amdgcn_s_setprio(0);

        // ---- biases + exp2; P stays in registers (C-layout == x16 B-layout)
        float2 tb = rts2[rbase - 2 * mt];
        short4v pf[4];
        #pragma unroll
        for (int nt = 0; nt < 4; nt++) {
            float tbx = (nt < 2) ? tb.x : tb.y;
            const f32x4& vv = (nt & 1) ? vvB : vvA;
            union { __bf16 e[4]; short4v s; } pk;
            #pragma unroll
            for (int r = 0; r < 4; r++) {
                float p = exp2f(sc[nt][r] + vv[r] + tbx);
                lp_s[nt] += p;
                pk.e[r] = (__bf16)p;
            }
            pf[nt] = pk.s;
        }

        // ---- O^T += V^T.P^T  (16x16x16, K = wave's 16-m slice) ----
        __builtin_amdgcn_s_setprio(1);
        #pragma unroll
        for (int nt = 0; nt < 4; nt++)
            #pragma unroll
            for (int dt = 0; dt < 4; dt++)
                o_p[dt][nt] = __builtin_amdgcn_mfma_f32_16x16x16bf16_1k(
                    vc[dt], pf[nt], o_p[dt][nt], 0, 0, 0);
        __builtin_amdgcn_s_setprio(0);

        // rotate prefetch
        if (mt + 1 < 24) {
            #pragma unroll
            for (int ks = 0; ks < 3; ks++) kc[ks] = kn[ks];
            #pragma unroll
            for (int dt = 0; dt < 4; dt++) vc[dt] = vn[dt];
        }
    }

    // ---- lp: reduce over quads (m within slice), publish per-wave partial
    #pragma unroll
    for (int nt = 0; nt < 4; nt++) {
        lp_s[nt] += __shfl_xor(lp_s[nt], 16);
        lp_s[nt] += __shfl_xor(lp_s[nt], 32);
    }
    if (quad == 0) {
        #pragma unroll
        for (int nt = 0; nt < 4; nt++) lps[w][nt * 16 + l16] = lp_s[nt];
    }

    // ---- O: cross-wave serialized add into Or (once per block) ----
    #pragma unroll
    for (int ws = 0; ws < 4; ws++) {
        if (w == ws) {
            #pragma unroll
            for (int dt = 0; dt < 4; dt++)
                #pragma unroll
                for (int nt = 0; nt < 4; nt++) {
                    float* dst = &Or[nt * 16 + l16][dt * 16 + quad * 4];
                    if (ws == 0) *(f32x4*)dst = o_p[dt][nt];
                    else {
                        f32x4 t = *(f32x4*)dst;
                        *(f32x4*)dst = t + o_p[dt][nt];
                    }
                }
        }
        __syncthreads();
    }

    // ---- normalize + store ----
    int n = tid >> 2, dq = tid & 3;
    float linv = 1.0f / (lps[0][n] + lps[1][n] + lps[2][n] + lps[3][n]);
    __bf16 ov[16];
    #pragma unroll
    for (int jj = 0; jj < 4; jj++) {
        f32x4 t = *(f32x4*)&Or[n][dq * 16 + jj * 4];
        ov[jj * 4 + 0] = (__bf16)(t[0] * linv);
        ov[jj * 4 + 1] = (__bf16)(t[1] * linv);
        ov[jj * 4 + 2] = (__bf16)(t[2] * linv);
        ov[jj * 4 + 3] = (__bf16)(t[3] * linv);
    }
    size_t abase = ((size_t)(b * NN) + n0 + n) * 512 + h * 64 + dq * 16;
    *(uint4*)(aout + abase)     = *(uint4*)&ov[0];
    *(uint4*)(aout + abase + 8) = *(uint4*)&ov[8];
}

extern "C" void kernel_launch(void* const* d_in, const int* in_sizes, int n_in,
                              void* d_out, int out_size, void* d_ws, size_t ws_size,
                              hipStream_t stream)
{
    const float* h_   = (const float*)d_in[0];
    const float* obs  = (const float*)d_in[1];
    const float* Wq   = (const float*)d_in[2];
    const float* bq   = (const float*)d_in[3];
    const float* Wk   = (const float*)d_in[4];
    const float* bk   = (const float*)d_in[5];
    const float* Wv   = (const float*)d_in[6];
    const float* bv   = (const float*)d_in[7];
    const float* Wo   = (const float*)d_in[8];
    const float* bo   = (const float*)d_in[9];
    const float* Woq  = (const float*)d_in[10];
    const float* boq  = (const float*)d_in[11];
    const float* Wok  = (const float*)d_in[12];
    const float* bok  = (const float*)d_in[13];
    const float* varb = (const float*)d_in[14];
    const float* rtb  = (const float*)d_in[15];
    float* out = (float*)d_out;

    char* ws = (char*)d_ws;
    __bf16* h_bf    = (__bf16*)ws;                 ws += (size_t)NBN * 512 * 2;
    __bf16* qarr    = (__bf16*)ws;                 ws += (size_t)NBN * 512 * 2;
    __bf16* vt      = (__bf16*)ws;                 ws += (size_t)NBN * 512 * 2;
    __bf16* kx      = (__bf16*)ws;                 ws += ((size_t)32 * NN * 96 + 64) * 2;
    __bf16* attnout = (__bf16*)ws;                 ws += (size_t)NBN * 512 * 2;
    __bf16* WcatT   = (__bf16*)ws;                 ws += (size_t)1536 * 512 * 2;
    __bf16* WoT     = (__bf16*)ws;                 ws += (size_t)512 * 512 * 2;
    float*  biascat = (float*)ws;                  ws += 1536 * 4;

    prep<<<dim3(2176), dim3(256), 0, stream>>>(
        h_, obs, Wq, Wk, Wv, Wo, bq, bk, bv, Wok, bok,
        h_bf, WcatT, WoT, biascat, kx);
    gemm_mfma<128, true><<<dim3(12, 48), dim3(256), 0, stream>>>(
        h_bf, WcatT, biascat, nullptr, qarr, kx, vt);
    attn_mfma<<<dim3(32, 24), dim3(256), 0, stream>>>(qarr, kx, vt, obs, Woq, boq,
                                                      varb, rtb, attnout);
    gemm_mfma<64, false><<<dim3(4, 96), dim3(256), 0, stream>>>(
        attnout, WoT, bo, out, nullptr, nullptr, nullptr);
}

// Round 5
// 185.578 us; speedup vs baseline: 1.0037x; 1.0037x over previous
//
#include <hip/hip_runtime.h>
#include <math.h>

typedef __bf16 bf16x8 __attribute__((ext_vector_type(8)));
typedef float f32x4 __attribute__((ext_vector_type(4)));
typedef short short4v __attribute__((ext_vector_type(4)));

#define NB 4
#define NT 48
#define NV 32
#define ND 512
#define NH 8
#define NN 1536   // T*V
#define NBN 6144  // B*N
#define L2E 1.44269504f

#define GLOAD_LDS(g, l) \
    __builtin_amdgcn_global_load_lds( \
        (const __attribute__((address_space(1))) void*)(g), \
        (__attribute__((address_space(3))) void*)(l), 16, 0, 0)

// ---------------------------------------------------------------------------
// prep: fused conv_h (blocks 0..1535) + weight transpose (1536..1791) +
// kx2 obs/zero fragment segments (1792..2175).  log2e folded into Wq/bq.
// kx2 layout (frag-major, attn wave-private):
//   frag(bh, mt, w, ks) of 512 elems; lane (quad,l16) holds 8 elems at
//   quad*128 + l16*8;  k = ks*32 + quad*8 + j.  ks=2: k 64..79 = oq, 80..95 = 0.
// ---------------------------------------------------------------------------
__global__ __launch_bounds__(256) void prep(
    const float* __restrict__ h, const float* __restrict__ obs,
    const float* __restrict__ Wq, const float* __restrict__ Wk,
    const float* __restrict__ Wv, const float* __restrict__ Wo,
    const float* __restrict__ bq, const float* __restrict__ bk,
    const float* __restrict__ bv,
    const float* __restrict__ Wok, const float* __restrict__ bok,
    __bf16* __restrict__ h_bf, __bf16* __restrict__ WcatT,
    __bf16* __restrict__ WoT, float* __restrict__ biascat,
    __bf16* __restrict__ kx)
{
    __shared__ float ts[64][68];
    const int tid = threadIdx.x;
    const int bx = blockIdx.x;
    if (bx < 1536) {
        int t = bx * 256 + tid;
        const float4* src = (const float4*)h + (size_t)t * 2;
        float4 a = src[0], b = src[1];
        __bf16 r[8] = {(__bf16)a.x, (__bf16)a.y, (__bf16)a.z, (__bf16)a.w,
                       (__bf16)b.x, (__bf16)b.y, (__bf16)b.z, (__bf16)b.w};
        *(uint4*)(h_bf + (size_t)t * 8) = *(uint4*)r;
    } else if (bx < 1792) {
        int bw = bx - 1536;
        const int p = bw >> 6, tile = bw & 63;
        const int k0 = (tile >> 3) * 64, c0 = (tile & 7) * 64;
        const float* W = (p == 0) ? Wq : (p == 1) ? Wk : (p == 2) ? Wv : Wo;
        const float scale = (p == 0) ? 0.125f * L2E : 1.0f;
        #pragma unroll
        for (int i = 0; i < 4; i++) {
            int r = (tid >> 4) + i * 16;
            float4 v = *(const float4*)(W + (size_t)(k0 + r) * 512 + c0 + (tid & 15) * 4);
            *(float4*)&ts[r][(tid & 15) * 4] = v;
        }
        __syncthreads();
        __bf16 tmp[16];
        #pragma unroll
        for (int j = 0; j < 16; j++)
            tmp[j] = (__bf16)(ts[(tid & 3) * 16 + j][tid >> 2] * scale);
        int crow = c0 + (tid >> 2);
        __bf16* dst = (p < 3)
            ? WcatT + ((size_t)(p * 512 + crow)) * 512 + k0 + (tid & 3) * 16
            : WoT   + ((size_t)crow) * 512 + k0 + (tid & 3) * 16;
        *(uint4*)dst = *(uint4*)tmp;
        *(uint4*)(dst + 8) = *(uint4*)(tmp + 8);
        if (p < 3 && k0 == 0 && tid < 64) {
            const float* bb = (p == 0) ? bq : (p == 1) ? bk : bv;
            biascat[p * 512 + c0 + tid] = bb[c0 + tid] * scale;
        }
    } else {
        int t = (bx - 1792) * 256 + tid;               // 0..98303
        int row = t >> 1, half = t & 1;                // row = bh*1536 + n
        int bh = row / NN, n = row - bh * NN;
        int mt = n >> 6, wv = (n >> 4) & 3, l16k = n & 15;
        __bf16* dst = kx + (((size_t)(bh * 24 + mt) * 4 + wv) * 3 + 2) * 512
                         + (half * 2) * 128 + l16k * 8;
        if (half == 0) {
            int hh = bh & 7;
            int b = bh >> 3;
            size_t bn = (size_t)b * NN + n;
            float o0 = obs[bn * 2], o1 = obs[bn * 2 + 1];
            int f = hh * 16;
            __bf16 tmp[16];
            #pragma unroll
            for (int j = 0; j < 16; j++)
                tmp[j] = (__bf16)(o0 * Wok[f + j] + o1 * Wok[128 + f + j] + bok[f + j]);
            *(uint4*)dst         = *(uint4*)tmp;
            *(uint4*)(dst + 128) = *(uint4*)(tmp + 8);
        } else {
            uint4 z = {0, 0, 0, 0};
            *(uint4*)dst         = z;
            *(uint4*)(dst + 128) = z;
        }
    }
}

// ---------------------------------------------------------------------------
// bf16 MFMA GEMM — software-pipelined (kept from R1, measured win).
// K-tile epilogue -> kx2 fragment layout; V-tile epilogue -> vt3 fragment
// layout for 16x16x16 PV A-frags (see R4 comments).  Unchanged from R4.
// ---------------------------------------------------------------------------
template<int TM, bool BF16OUT>
__global__ __launch_bounds__(256) void gemm_mfma(
    const __bf16* __restrict__ A, const __bf16* __restrict__ Bt,
    const float* __restrict__ bias, float* __restrict__ Cf,
    __bf16* __restrict__ qarr, __bf16* __restrict__ kx,
    __bf16* __restrict__ vt)
{
    constexpr int MT = TM / 32;
    __shared__ __align__(16) char smem[34816];
    char* const As0 = smem;
    char* const As1 = smem + TM * 64;
    char* const Bs0 = smem + TM * 128;
    char* const Bs1 = smem + TM * 128 + 8192;
    const int tid = threadIdx.x;
    const int w = tid >> 6, lane = tid & 63;
    const int quad = lane >> 4, l16 = lane & 15;
    const int wm = w >> 1, wn = w & 1;
    const int n0 = blockIdx.x * 128, m0 = blockIdx.y * TM;

    const int sm = tid >> 2;
    const int sk = ((tid & 3) ^ ((sm >> 1) & 3)) * 8;
    const __bf16* aptr = A  + (size_t)(m0 + sm) * 512 + sk;
    const __bf16* bptr = Bt + (size_t)(n0 + sm) * 512 + sk;

    f32x4 zero4 = {0.f, 0.f, 0.f, 0.f};
    f32x4 acc[MT][4];
    #pragma unroll
    for (int i = 0; i < MT; i++)
        #pragma unroll
        for (int j = 0; j < 4; j++) acc[i][j] = zero4;

    auto STAGE = [&](char* dA, char* dB, int kt) {
        GLOAD_LDS(aptr + kt, dA + tid * 16);
        if (TM == 128) GLOAD_LDS(aptr + 64 * 512 + kt, dA + 4096 + tid * 16);
        GLOAD_LDS(bptr + kt, dB + tid * 16);
        GLOAD_LDS(bptr + 64 * 512 + kt, dB + 4096 + tid * 16);
    };
    auto COMPUTE = [&](const char* Asb, const char* Bsb) {
        bf16x8 af[MT], bfr[4];
        #pragma unroll
        for (int mt = 0; mt < MT; mt++) {
            int rr = wm * (TM / 2) + mt * 16 + l16;
            af[mt] = *(const bf16x8*)(Asb + rr * 64 + (quad ^ ((rr >> 1) & 3)) * 16);
        }
        #pragma unroll
        for (int nt = 0; nt < 4; nt++) {
            int rr = wn * 64 + nt * 16 + l16;
            bfr[nt] = *(const bf16x8*)(Bsb + rr * 64 + (quad ^ ((rr >> 1) & 3)) * 16);
        }
        #pragma unroll
        for (int mt = 0; mt < MT; mt++)
            #pragma unroll
            for (int nt = 0; nt < 4; nt++)
                acc[mt][nt] = __builtin_amdgcn_mfma_f32_16x16x32_bf16(
                    af[mt], bfr[nt], acc[mt][nt], 0, 0, 0);
    };

    STAGE(As0, Bs0, 0);
    asm volatile("s_waitcnt vmcnt(0)" ::: "memory");
    __builtin_amdgcn_s_barrier();
    for (int kt = 0; kt < 512; kt += 64) {
        STAGE(As1, Bs1, kt + 32);          // always valid: last is kt=448 -> 480
        COMPUTE(As0, Bs0);
        asm volatile("s_waitcnt vmcnt(0)" ::: "memory");
        __builtin_amdgcn_s_barrier();
        if (kt + 64 < 512) STAGE(As0, Bs0, kt + 64);
        COMPUTE(As1, Bs1);
        asm volatile("s_waitcnt vmcnt(0)" ::: "memory");
        __builtin_amdgcn_s_barrier();
    }

    __syncthreads();   // frag reads done; smem becomes C-stage
    if (BF16OUT) {
        if (n0 >= 1024) {
            // ---- V tile: stage TRANSPOSED (CsT[col][136 rows]), write vt3 ----
            __bf16* CsT = (__bf16*)smem;
            #pragma unroll
            for (int nt = 0; nt < 4; nt++) {
                int cl = wn * 64 + nt * 16 + l16;
                float bia = bias[n0 + cl];
                #pragma unroll
                for (int mt = 0; mt < MT; mt++) {
                    int rl0 = wm * (TM / 2) + mt * 16 + quad * 4;
                    __bf16 pk[4];
                    #pragma unroll
                    for (int r = 0; r < 4; r++)
                        pk[r] = (__bf16)(acc[mt][nt][r] + bia);
                    *(uint2*)&CsT[cl * 136 + rl0] = *(uint2*)pk;
                }
            }
            __syncthreads();
            int cl = tid >> 1, half = tid & 1;
            int f0 = (n0 + cl) & 511;
            int hh = f0 >> 6, d = f0 & 63;
            int dt = d >> 4, l16v = d & 15;
            int bidx = m0 / NN, nm = m0 - bidx * NN;
            int bh = bidx * 8 + hh;
            int mtv = (nm >> 6) + half;
            #pragma unroll
            for (int j = 0; j < 8; j++) {
                uint4 v = *(uint4*)&CsT[cl * 136 + half * 64 + j * 8];
                __bf16* pp = (__bf16*)&v;
                size_t fo = (((size_t)(bh * 24 + mtv) * 4 + (j >> 1)) * 4 + dt) * 256;
                int q0 = (j & 1) * 2;
                *(uint2*)(vt + fo + q0 * 64 + l16v * 4)       = *(uint2*)&pp[0];
                *(uint2*)(vt + fo + (q0 + 1) * 64 + l16v * 4) = *(uint2*)&pp[4];
            }
        } else {
            // ---- Q/K tile: row-major stage, routed stores ----
            __bf16* Cs = (__bf16*)smem;               // [TM][132]
            #pragma unroll
            for (int mt = 0; mt < MT; mt++)
                #pragma unroll
                for (int nt = 0; nt < 4; nt++) {
                    int cl = wn * 64 + nt * 16 + l16;
                    float bia = bias[n0 + cl];
                    #pragma unroll
                    for (int r = 0; r < 4; r++) {
                        int rl = wm * (TM / 2) + mt * 16 + quad * 4 + r;
                        Cs[rl * 132 + cl] = (__bf16)(acc[mt][nt][r] + bia);
                    }
                }
            __syncthreads();
            int rl = tid >> 1, hb = tid & 1;
            int grow = m0 + rl;
            int col0 = n0 + hb * 64;
            int p = col0 >> 9, f0 = col0 & 511, hh = f0 >> 6;
            int bidx = grow / NN, n = grow - bidx * NN;
            if (p == 0) {
                __bf16* dst = qarr + (size_t)grow * 512 + f0;
                #pragma unroll
                for (int j = 0; j < 8; j++) {
                    uint2 lo = *(uint2*)&Cs[rl * 132 + hb * 64 + j * 8];
                    uint2 hi = *(uint2*)&Cs[rl * 132 + hb * 64 + j * 8 + 4];
                    uint4 v = {lo.x, lo.y, hi.x, hi.y};
                    *(uint4*)(dst + j * 8) = v;
                }
            } else {
                int mtk = n >> 6, wv = (n >> 4) & 3, l16k = n & 15;
                size_t fb = ((size_t)((bidx * 8 + hh) * 24 + mtk) * 4 + wv) * 1536;
                #pragma unroll
                for (int j = 0; j < 8; j++) {
                    uint2 lo = *(uint2*)&Cs[rl * 132 + hb * 64 + j * 8];
                    uint2 hi = *(uint2*)&Cs[rl * 132 + hb * 64 + j * 8 + 4];
                    uint4 v = {lo.x, lo.y, hi.x, hi.y};
                    *(uint4*)(kx + fb + (j >> 2) * 512 + (j & 3) * 128 + l16k * 8) = v;
                }
            }
        }
    } else {
        float* Csf = (float*)smem;                // [64][132]
        #pragma unroll
        for (int mt = 0; mt < MT; mt++)
            #pragma unroll
            for (int nt = 0; nt < 4; nt++) {
                int cl = wn * 64 + nt * 16 + l16;
                float bia = bias[n0 + cl];
                #pragma unroll
                for (int r = 0; r < 4; r++) {
                    int rl = wm * (TM / 2) + mt * 16 + quad * 4 + r;
                    Csf[rl * 132 + cl] = acc[mt][nt][r] + bia;
                }
            }
        __syncthreads();
        int rl = tid >> 2, q4 = tid & 3;
        float* dst = Cf + (size_t)(m0 + rl) * 512 + n0 + q4 * 32;
        #pragma unroll
        for (int j = 0; j < 8; j++) {
            uint4 v = *(uint4*)&Csf[rl * 132 + q4 * 32 + j * 4];
            *(uint4*)(dst + j * 4) = v;
        }
    }
}

// ---------------------------------------------------------------------------
// Flash attention, barrier-free m-split (R4 structure) with R5 VALU cuts:
//  * Q fragments live in LDS (block-uniform; 12 KB, unioned with Or) — frees
//    48 VGPRs of loop-resident state; 12 ds_read_b128/tile, imm offsets.
//  * mt unrolled x2 with ping-pong prefetch register sets — no rotation movs.
//  * lp computed by MFMA-with-ones (replaces 16 v_add/tile + end shuffles).
// Loop still has zero barriers; one LDS O/lp reduction per block at the end.
// ---------------------------------------------------------------------------
__global__ __launch_bounds__(256) void attn_mfma(
    const __bf16* __restrict__ qarr, const __bf16* __restrict__ kx,
    const __bf16* __restrict__ vt, const float* __restrict__ obs,
    const float* __restrict__ Woq, const float* __restrict__ boq,
    const float* __restrict__ varb, const float* __restrict__ rtb,
    __bf16* __restrict__ aout)
{
    __shared__ __align__(16) char smu[64 * 68 * 4];  // union: Qs (loop) / Or (end)
    __shared__ float lps[4][64];       // per-wave lp partials [w][n]
    __shared__ float2 rts2[96];        // (rts[i], rts[i+1]) pairs

    float (*Or)[68] = (float (*)[68])smu;
    __bf16* Qs = (__bf16*)smu;         // [frag 0..11][lane][8], frag = nt*3+ks

    const int tid = threadIdx.x;
    const int w = tid >> 6, lane = tid & 63;
    const int quad = lane >> 4, l16 = lane & 15;
    const int bh = blockIdx.x, qt = blockIdx.y;   // XCD-locality swizzle
    const int b = bh >> 3, h = bh & 7;
    const int n0 = qt * 64;

    // wave-private K/V fragment bases (lane-linear within each frag)
    const __bf16* kwb = kx + ((size_t)bh * 24 * 4 + w) * 1536 + lane * 8;
    const __bf16* vwb = vt + ((size_t)bh * 24 * 4 + w) * 1024 + lane * 4;

    // ---- prefetch tiles 0 and 1 into ping-pong register sets (issue early)
    bf16x8 kA[3], kB[3]; short4v vA_[4], vB_[4];
    #pragma unroll
    for (int ks = 0; ks < 3; ks++) kA[ks] = *(const bf16x8*)(kwb + ks * 512);
    #pragma unroll
    for (int dt = 0; dt < 4; dt++) vA_[dt] = *(const short4v*)(vwb + dt * 256);
    #pragma unroll
    for (int ks = 0; ks < 3; ks++) kB[ks] = *(const bf16x8*)(kwb + 6144 + ks * 512);
    #pragma unroll
    for (int dt = 0; dt < 4; dt++) vB_[dt] = *(const short4v*)(vwb + 4096 + dt * 256);

    if (tid < 95) {
        float a = rtb[h * 95 + tid] * L2E;
        float c = (tid < 94) ? rtb[h * 95 + tid + 1] * L2E : 0.f;
        rts2[tid].x = a;
        rts2[tid].y = c;
    }

    // ---- Q fragments -> LDS (wave w computes the nt==w fragments; all waves
    // read all of them per tile).  Same values as R4's qf[w][*].
    {
        const size_t qrow = (size_t)(b * NN + n0 + w * 16 + l16);
        bf16x8 f0 = *(const bf16x8*)(qarr + qrow * 512 + h * 64 + quad * 8);
        bf16x8 f1 = *(const bf16x8*)(qarr + qrow * 512 + h * 64 + 32 + quad * 8);
        uint4 a2u = {0u, 0u, 0u, 0u};
        if (quad < 2) {
            float o0 = obs[qrow * 2], o1 = obs[qrow * 2 + 1];
            int f = h * 16 + quad * 8;
            const float scq = 0.25f * L2E;
            __bf16 tmp[8];
            #pragma unroll
            for (int j = 0; j < 8; j++)
                tmp[j] = (__bf16)(scq * (o0 * Woq[f + j] + o1 * Woq[128 + f + j]
                                         + boq[f + j]));
            a2u = *(uint4*)tmp;
        }
        __bf16* qdst = Qs + ((size_t)(w * 3) * 64 + lane) * 8;
        *(bf16x8*)(qdst)        = f0;
        *(bf16x8*)(qdst + 512)  = f1;
        *(bf16x8*)(qdst + 1024) = *(bf16x8*)&a2u;
    }

    // var-bias: n&31 = (nt&1)*16 + l16;  m&31 = (w&1)*16 + quad*4 + r
    const float* vbp = varb + h * 1024 + (w & 1) * 16 + quad * 4;
    f32x4 vvA = *(const f32x4*)(vbp + l16 * 32);
    f32x4 vvB = *(const f32x4*)(vbp + (16 + l16) * 32);
    vvA *= L2E; vvB *= L2E;

    const int rbase = 2 * qt - (w >> 1) + 47;
    const __bf16* qsl = Qs + lane * 8;

    // ones fragment for the lp MFMA (A operand, all 1.0)
    union { __bf16 e[4]; short4v s; } one_u;
    #pragma unroll
    for (int j = 0; j < 4; j++) one_u.e[j] = (__bf16)1.0f;
    const short4v ones = one_u.s;

    f32x4 zero4 = {0.f, 0.f, 0.f, 0.f};
    f32x4 o_p[4][4];                  // [dt][nt]
    f32x4 lpa[4];                     // lp accumulators (MFMA-ones)
    #pragma unroll
    for (int i = 0; i < 4; i++) {
        lpa[i] = zero4;
        #pragma unroll
        for (int j = 0; j < 4; j++) o_p[i][j] = zero4;
    }

    __syncthreads();                  // Qs + rts2 visible to all waves

    auto COMPUTE = [&](const bf16x8* kc, const short4v* vc, int mt) {
        float2 tb = rts2[rbase - 2 * mt];
        #pragma unroll
        for (int nt = 0; nt < 4; nt++) {
            bf16x8 q0 = *(const bf16x8*)(qsl + (nt * 3 + 0) * 512);
            bf16x8 q1 = *(const bf16x8*)(qsl + (nt * 3 + 1) * 512);
            bf16x8 q2 = *(const bf16x8*)(qsl + (nt * 3 + 2) * 512);
            f32x4 d = zero4;
            d = __builtin_amdgcn_mfma_f32_16x16x32_bf16(kc[0], q0, d, 0, 0, 0);
            d = __builtin_amdgcn_mfma_f32_16x16x32_bf16(kc[1], q1, d, 0, 0, 0);
            d = __builtin_amdgcn_mfma_f32_16x16x32_bf16(kc[2], q2, d, 0, 0, 0);
            float tbx = (nt < 2) ? tb.x : tb.y;
            const f32x4& vv = (nt & 1) ? vvB : vvA;
            union { __bf16 e[4]; short4v s; } pk;
            #pragma unroll
            for (int r = 0; r < 4; r++)
                pk.e[r] = (__bf16)exp2f(d[r] + vv[r] + tbx);
            short4v pf = pk.s;
            lpa[nt] = __builtin_amdgcn_mfma_f32_16x16x16bf16_1k(
                ones, pf, lpa[nt], 0, 0, 0);
            #pragma unroll
            for (int dt = 0; dt < 4; dt++)
                o_p[dt][nt] = __builtin_amdgcn_mfma_f32_16x16x16bf16_1k(
                    vc[dt], pf, o_p[dt][nt], 0, 0, 0);
        }
    };

    // main loop: tiles (2i, 2i+1); loads refill consumed sets, no rotation
    for (int i = 0; i < 11; i++) {
        COMPUTE(kA, vA_, 2 * i);
        {
            const __bf16* kp = kwb + (size_t)(2 * i + 2) * 6144;
            const __bf16* vp = vwb + (size_t)(2 * i + 2) * 4096;
            #pragma unroll
            for (int ks = 0; ks < 3; ks++) kA[ks] = *(const bf16x8*)(kp + ks * 512);
            #pragma unroll
            for (int dt = 0; dt < 4; dt++) vA_[dt] = *(const short4v*)(vp + dt * 256);
        }
        COMPUTE(kB, vB_, 2 * i + 1);
        {
            const __bf16* kp = kwb + (size_t)(2 * i + 3) * 6144;
            const __bf16* vp = vwb + (size_t)(2 * i + 3) * 4096;
            #pragma unroll
            for (int ks = 0; ks < 3; ks++) kB[ks] = *(const bf16x8*)(kp + ks * 512);
            #pragma unroll
            for (int dt = 0; dt < 4; dt++) vB_[dt] = *(const short4v*)(vp + dt * 256);
        }
    }
    COMPUTE(kA, vA_, 22);
    COMPUTE(kB, vB_, 23);

    // ---- lp publish: lpa[nt][r] == lp[n=nt*16+l16] partial (all r, all quads)
    if (quad == 0) {
        #pragma unroll
        for (int nt = 0; nt < 4; nt++) lps[w][nt * 16 + l16] = lpa[nt][0];
    }
    __syncthreads();   // all Qs reads done (smu becomes Or) + lps visible later

    // ---- O: cross-wave serialized add into Or (once per block) ----
    #pragma unroll
    for (int ws = 0; ws < 4; ws++) {
        if (w == ws) {
            #pragma unroll
            for (int dt = 0; dt < 4; dt++)
                #pragma unroll
                for (int nt = 0; nt < 4; nt++) {
                    float* dst = &Or[nt * 16 + l16][dt * 16 + quad * 4];
                    if (ws == 0) *(f32x4*)dst = o_p[dt][nt];
                    else {
                        f32x4 t = *(f32x4*)dst;
                        *(f32x4*)dst = t + o_p[dt][nt];
                    }
                }
        }
        __syncthreads();
    }

    // ---- normalize + store ----
    int n = tid >> 2, dq = tid & 3;
    float linv = 1.0f / (lps[0][n] + lps[1][n] + lps[2][n] + lps[3][n]);
    __bf16 ov[16];
    #pragma unroll
    for (int jj = 0; jj < 4; jj++) {
        f32x4 t = *(f32x4*)&Or[n][dq * 16 + jj * 4];
        ov[jj * 4 + 0] = (__bf16)(t[0] * linv);
        ov[jj * 4 + 1] = (__bf16)(t[1] * linv);
        ov[jj * 4 + 2] = (__bf16)(t[2] * linv);
        ov[jj * 4 + 3] = (__bf16)(t[3] * linv);
    }
    size_t abase = ((size_t)(b * NN) + n0 + n) * 512 + h * 64 + dq * 16;
    *(uint4*)(aout + abase)     = *(uint4*)&ov[0];
    *(uint4*)(aout + abase + 8) = *(uint4*)&ov[8];
}

extern "C" void kernel_launch(void* const* d_in, const int* in_sizes, int n_in,
                              void* d_out, int out_size, void* d_ws, size_t ws_size,
                              hipStream_t stream)
{
    const float* h_   = (const float*)d_in[0];
    const float* obs  = (const float*)d_in[1];
    const float* Wq   = (const float*)d_in[2];
    const float* bq   = (const float*)d_in[3];
    const float* Wk   = (const float*)d_in[4];
    const float* bk   = (const float*)d_in[5];
    const float* Wv   = (const float*)d_in[6];
    const float* bv   = (const float*)d_in[7];
    const float* Wo   = (const float*)d_in[8];
    const float* bo   = (const float*)d_in[9];
    const float* Woq  = (const float*)d_in[10];
    const float* boq  = (const float*)d_in[11];
    const float* Wok  = (const float*)d_in[12];
    const float* bok  = (const float*)d_in[13];
    const float* varb = (const float*)d_in[14];
    const float* rtb  = (const float*)d_in[15];
    float* out = (float*)d_out;

    char* ws = (char*)d_ws;
    __bf16* h_bf    = (__bf16*)ws;                 ws += (size_t)NBN * 512 * 2;
    __bf16* qarr    = (__bf16*)ws;                 ws += (size_t)NBN * 512 * 2;
    __bf16* vt      = (__bf16*)ws;                 ws += (size_t)NBN * 512 * 2;
    __bf16* kx      = (__bf16*)ws;                 ws += ((size_t)32 * NN * 96 + 64) * 2;
    __bf16* attnout = (__bf16*)ws;                 ws += (size_t)NBN * 512 * 2;
    __bf16* WcatT   = (__bf16*)ws;                 ws += (size_t)1536 * 512 * 2;
    __bf16* WoT     = (__bf16*)ws;                 ws += (size_t)512 * 512 * 2;
    float*  biascat = (float*)ws;                  ws += 1536 * 4;

    prep<<<dim3(2176), dim3(256), 0, stream>>>(
        h_, obs, Wq, Wk, Wv, Wo, bq, bk, bv, Wok, bok,
        h_bf, WcatT, WoT, biascat, kx);
    gemm_mfma<128, true><<<dim3(12, 48), dim3(256), 0, stream>>>(
        h_bf, WcatT, biascat, nullptr, qarr, kx, vt);
    attn_mfma<<<dim3(32, 24), dim3(256), 0, stream>>>(qarr, kx, vt, obs, Woq, boq,
                                                      varb, rtb, attnout);
    gemm_mfma<64, false><<<dim3(4, 96), dim3(256), 0, stream>>>(
        attnout, WoT, bo, out, nullptr, nullptr, nullptr);
}

// Round 6
// 176.633 us; speedup vs baseline: 1.0546x; 1.0506x over previous
//
#include <hip/hip_runtime.h>
#include <math.h>

typedef __bf16 bf16x8 __attribute__((ext_vector_type(8)));
typedef float f32x4 __attribute__((ext_vector_type(4)));
typedef short short4v __attribute__((ext_vector_type(4)));
typedef short short8v __attribute__((ext_vector_type(8)));

#define NB 4
#define NT 48
#define NV 32
#define ND 512
#define NH 8
#define NN 1536   // T*V
#define NBN 6144  // B*N
#define L2E 1.44269504f

#define GLOAD_LDS(g, l) \
    __builtin_amdgcn_global_load_lds( \
        (const __attribute__((address_space(1))) void*)(g), \
        (__attribute__((address_space(3))) void*)(l), 16, 0, 0)

// ---------------------------------------------------------------------------
// prep: fused conv_h (blocks 0..1535) + weight transpose (1536..1791) +
// kx obs/zero segments (1792..2175).  log2e folded into Wq/bq scale.
// kx layout = R3 row-major: kx[(bh*NN + n)*96 + k], k 0..63 content (gemm),
// 64..79 oq, 80..95 zeros (prep).
// ---------------------------------------------------------------------------
__global__ __launch_bounds__(256) void prep(
    const float* __restrict__ h, const float* __restrict__ obs,
    const float* __restrict__ Wq, const float* __restrict__ Wk,
    const float* __restrict__ Wv, const float* __restrict__ Wo,
    const float* __restrict__ bq, const float* __restrict__ bk,
    const float* __restrict__ bv,
    const float* __restrict__ Wok, const float* __restrict__ bok,
    __bf16* __restrict__ h_bf, __bf16* __restrict__ WcatT,
    __bf16* __restrict__ WoT, float* __restrict__ biascat,
    __bf16* __restrict__ kx)
{
    __shared__ float ts[64][68];
    const int tid = threadIdx.x;
    const int bx = blockIdx.x;
    if (bx < 1536) {
        int t = bx * 256 + tid;
        const float4* src = (const float4*)h + (size_t)t * 2;
        float4 a = src[0], b = src[1];
        __bf16 r[8] = {(__bf16)a.x, (__bf16)a.y, (__bf16)a.z, (__bf16)a.w,
                       (__bf16)b.x, (__bf16)b.y, (__bf16)b.z, (__bf16)b.w};
        *(uint4*)(h_bf + (size_t)t * 8) = *(uint4*)r;
    } else if (bx < 1792) {
        int bw = bx - 1536;
        const int p = bw >> 6, tile = bw & 63;
        const int k0 = (tile >> 3) * 64, c0 = (tile & 7) * 64;
        const float* W = (p == 0) ? Wq : (p == 1) ? Wk : (p == 2) ? Wv : Wo;
        const float scale = (p == 0) ? 0.125f * L2E : 1.0f;
        #pragma unroll
        for (int i = 0; i < 4; i++) {
            int r = (tid >> 4) + i * 16;
            float4 v = *(const float4*)(W + (size_t)(k0 + r) * 512 + c0 + (tid & 15) * 4);
            *(float4*)&ts[r][(tid & 15) * 4] = v;
        }
        __syncthreads();
        __bf16 tmp[16];
        #pragma unroll
        for (int j = 0; j < 16; j++)
            tmp[j] = (__bf16)(ts[(tid & 3) * 16 + j][tid >> 2] * scale);
        int crow = c0 + (tid >> 2);
        __bf16* dst = (p < 3)
            ? WcatT + ((size_t)(p * 512 + crow)) * 512 + k0 + (tid & 3) * 16
            : WoT   + ((size_t)crow) * 512 + k0 + (tid & 3) * 16;
        *(uint4*)dst = *(uint4*)tmp;
        *(uint4*)(dst + 8) = *(uint4*)(tmp + 8);
        if (p < 3 && k0 == 0 && tid < 64) {
            const float* bb = (p == 0) ? bq : (p == 1) ? bk : bv;
            biascat[p * 512 + c0 + tid] = bb[c0 + tid] * scale;
        }
    } else {
        int t = (bx - 1792) * 256 + tid;               // 0..98303
        int row = t >> 1, half = t & 1;                // row = bh*1536 + n
        __bf16* dst = kx + (size_t)row * 96 + 64 + half * 16;
        if (half == 0) {
            int bh = row / NN, n = row - bh * NN;
            int b = bh >> 3, hh = bh & 7;
            size_t bn = (size_t)b * NN + n;
            float o0 = obs[bn * 2], o1 = obs[bn * 2 + 1];
            int f = hh * 16;
            __bf16 tmp[16];
            #pragma unroll
            for (int j = 0; j < 16; j++)
                tmp[j] = (__bf16)(o0 * Wok[f + j] + o1 * Wok[128 + f + j] + bok[f + j]);
            *(uint4*)dst       = *(uint4*)tmp;
            *(uint4*)(dst + 8) = *(uint4*)(tmp + 8);
        } else {
            uint4 z = {0, 0, 0, 0};
            *(uint4*)dst       = z;
            *(uint4*)(dst + 8) = z;
        }
    }
}

// ---------------------------------------------------------------------------
// bf16 MFMA GEMM — software-pipelined (R1, kept).  K-tile epilogue -> R3
// row-major kx.  V-tile epilogue -> vt4 packed-pair fragment layout for
// 16x16x16 PV A-frags:
//   slot fi = wv*2 + (dt>>1), addr = ((bh*24+mt)*8 + fi)*512 + lane*8 +
//   (dt&1)*4 + jj;  lane=(quad,l16) holds d = dt*16+l16, m16 = quad*4+jj.
// ---------------------------------------------------------------------------
template<int TM, bool BF16OUT>
__global__ __launch_bounds__(256) void gemm_mfma(
    const __bf16* __restrict__ A, const __bf16* __restrict__ Bt,
    const float* __restrict__ bias, float* __restrict__ Cf,
    __bf16* __restrict__ qarr, __bf16* __restrict__ kx,
    __bf16* __restrict__ vt)
{
    constexpr int MT = TM / 32;
    __shared__ __align__(16) char smem[34816];
    char* const As0 = smem;
    char* const As1 = smem + TM * 64;
    char* const Bs0 = smem + TM * 128;
    char* const Bs1 = smem + TM * 128 + 8192;
    const int tid = threadIdx.x;
    const int w = tid >> 6, lane = tid & 63;
    const int quad = lane >> 4, l16 = lane & 15;
    const int wm = w >> 1, wn = w & 1;
    const int n0 = blockIdx.x * 128, m0 = blockIdx.y * TM;

    const int sm = tid >> 2;
    const int sk = ((tid & 3) ^ ((sm >> 1) & 3)) * 8;
    const __bf16* aptr = A  + (size_t)(m0 + sm) * 512 + sk;
    const __bf16* bptr = Bt + (size_t)(n0 + sm) * 512 + sk;

    f32x4 zero4 = {0.f, 0.f, 0.f, 0.f};
    f32x4 acc[MT][4];
    #pragma unroll
    for (int i = 0; i < MT; i++)
        #pragma unroll
        for (int j = 0; j < 4; j++) acc[i][j] = zero4;

    auto STAGE = [&](char* dA, char* dB, int kt) {
        GLOAD_LDS(aptr + kt, dA + tid * 16);
        if (TM == 128) GLOAD_LDS(aptr + 64 * 512 + kt, dA + 4096 + tid * 16);
        GLOAD_LDS(bptr + kt, dB + tid * 16);
        GLOAD_LDS(bptr + 64 * 512 + kt, dB + 4096 + tid * 16);
    };
    auto COMPUTE = [&](const char* Asb, const char* Bsb) {
        bf16x8 af[MT], bfr[4];
        #pragma unroll
        for (int mt = 0; mt < MT; mt++) {
            int rr = wm * (TM / 2) + mt * 16 + l16;
            af[mt] = *(const bf16x8*)(Asb + rr * 64 + (quad ^ ((rr >> 1) & 3)) * 16);
        }
        #pragma unroll
        for (int nt = 0; nt < 4; nt++) {
            int rr = wn * 64 + nt * 16 + l16;
            bfr[nt] = *(const bf16x8*)(Bsb + rr * 64 + (quad ^ ((rr >> 1) & 3)) * 16);
        }
        #pragma unroll
        for (int mt = 0; mt < MT; mt++)
            #pragma unroll
            for (int nt = 0; nt < 4; nt++)
                acc[mt][nt] = __builtin_amdgcn_mfma_f32_16x16x32_bf16(
                    af[mt], bfr[nt], acc[mt][nt], 0, 0, 0);
    };

    STAGE(As0, Bs0, 0);
    asm volatile("s_waitcnt vmcnt(0)" ::: "memory");
    __builtin_amdgcn_s_barrier();
    for (int kt = 0; kt < 512; kt += 64) {
        STAGE(As1, Bs1, kt + 32);          // always valid: last is kt=448 -> 480
        COMPUTE(As0, Bs0);
        asm volatile("s_waitcnt vmcnt(0)" ::: "memory");
        __builtin_amdgcn_s_barrier();
        if (kt + 64 < 512) STAGE(As0, Bs0, kt + 64);
        COMPUTE(As1, Bs1);
        asm volatile("s_waitcnt vmcnt(0)" ::: "memory");
        __builtin_amdgcn_s_barrier();
    }

    __syncthreads();   // frag reads done; smem becomes C-stage
    if (BF16OUT) {
        if (n0 >= 1024) {
            // ---- V tile: stage TRANSPOSED (CsT[col][136 rows]), write vt4 ----
            __bf16* CsT = (__bf16*)smem;
            #pragma unroll
            for (int nt = 0; nt < 4; nt++) {
                int cl = wn * 64 + nt * 16 + l16;
                float bia = bias[n0 + cl];
                #pragma unroll
                for (int mt = 0; mt < MT; mt++) {
                    int rl0 = wm * (TM / 2) + mt * 16 + quad * 4;
                    __bf16 pk[4];
                    #pragma unroll
                    for (int r = 0; r < 4; r++)
                        pk[r] = (__bf16)(acc[mt][nt][r] + bia);
                    *(uint2*)&CsT[cl * 136 + rl0] = *(uint2*)pk;
                }
            }
            __syncthreads();
            int cl = tid >> 1, half = tid & 1;
            int f0 = (n0 + cl) & 511;
            int hh = f0 >> 6, d = f0 & 63;
            int dt = d >> 4, l16v = d & 15;
            int bidx = m0 / NN, nm = m0 - bidx * NN;
            int bh = bidx * 8 + hh;
            int mtv = (nm >> 6) + half;
            #pragma unroll
            for (int j = 0; j < 8; j++) {
                uint4 v = *(uint4*)&CsT[cl * 136 + half * 64 + j * 8];
                __bf16* pp = (__bf16*)&v;
                int q0 = (j & 1) * 2;
                size_t fo = ((size_t)(bh * 24 + mtv) * 8 + (j >> 1) * 2 + (dt >> 1)) * 512
                            + (dt & 1) * 4 + l16v * 8;
                *(uint2*)(vt + fo + q0 * 128)       = *(uint2*)&pp[0];
                *(uint2*)(vt + fo + (q0 + 1) * 128) = *(uint2*)&pp[4];
            }
        } else {
            // ---- Q/K tile: row-major stage, routed stores (R3 form) ----
            __bf16* Cs = (__bf16*)smem;               // [TM][132]
            #pragma unroll
            for (int mt = 0; mt < MT; mt++)
                #pragma unroll
                for (int nt = 0; nt < 4; nt++) {
                    int cl = wn * 64 + nt * 16 + l16;
                    float bia = bias[n0 + cl];
                    #pragma unroll
                    for (int r = 0; r < 4; r++) {
                        int rl = wm * (TM / 2) + mt * 16 + quad * 4 + r;
                        Cs[rl * 132 + cl] = (__bf16)(acc[mt][nt][r] + bia);
                    }
                }
            __syncthreads();
            int rl = tid >> 1, hb = tid & 1;
            int grow = m0 + rl;
            int col0 = n0 + hb * 64;
            int p = col0 >> 9, f0 = col0 & 511, hh = f0 >> 6;
            int bidx = grow / NN, n = grow - bidx * NN;
            __bf16* dst = (p == 0) ? qarr + (size_t)grow * 512 + f0
                                   : kx + ((size_t)(bidx * 8 + hh) * NN + n) * 96;
            #pragma unroll
            for (int j = 0; j < 8; j++) {
                uint2 lo = *(uint2*)&Cs[rl * 132 + hb * 64 + j * 8];
                uint2 hi = *(uint2*)&Cs[rl * 132 + hb * 64 + j * 8 + 4];
                uint4 v = {lo.x, lo.y, hi.x, hi.y};
                *(uint4*)(dst + j * 8) = v;
            }
        }
    } else {
        float* Csf = (float*)smem;                // [64][132]
        #pragma unroll
        for (int mt = 0; mt < MT; mt++)
            #pragma unroll
            for (int nt = 0; nt < 4; nt++) {
                int cl = wn * 64 + nt * 16 + l16;
                float bia = bias[n0 + cl];
                #pragma unroll
                for (int r = 0; r < 4; r++) {
                    int rl = wm * (TM / 2) + mt * 16 + quad * 4 + r;
                    Csf[rl * 132 + cl] = acc[mt][nt][r] + bia;
                }
            }
        __syncthreads();
        int rl = tid >> 2, q4 = tid & 3;
        float* dst = Cf + (size_t)(m0 + rl) * 512 + n0 + q4 * 32;
        #pragma unroll
        for (int j = 0; j < 8; j++) {
            uint4 v = *(uint4*)&Csf[rl * 132 + q4 * 32 + j * 4];
            *(uint4*)(dst + j * 4) = v;
        }
    }
}

// ---------------------------------------------------------------------------
// Flash attention, n-split (R3 orientation) with R6 structure:
//  * P in REGISTERS: PV uses 16x16x16 MFMAs whose B-frag layout (k=quad*4+j,
//    col=l16) equals the QK C-layout (m=quad*4+r, n=l16) — Ps LDS eliminated.
//    (Layout equality HW-verified by R4/R5 passing runs.)
//  * V from registers via vt4 packed-pair frags (8 x 16B loads/tile).
//  * Double K-tile LDS (Ks[2], 32KB): QK of BOTH tiles before one barrier,
//    next-pair staging covered by softmax+PV of both tiles.  2 barriers /
//    2 tiles (half of R3).  LDS 33.2 KB -> 3 blocks/CU.
//  * lp via MFMA-with-ones (R5-verified numerics): no adds, no end shuffles.
// __launch_bounds__(256,3) pins 3 waves/SIMD (= 3 blocks/CU residency).
// ---------------------------------------------------------------------------
__global__ __launch_bounds__(256, 3) void attn_mfma(
    const __bf16* __restrict__ qarr, const __bf16* __restrict__ kx,
    const __bf16* __restrict__ vt, const float* __restrict__ obs,
    const float* __restrict__ Woq, const float* __restrict__ boq,
    const float* __restrict__ varb, const float* __restrict__ rtb,
    __bf16* __restrict__ aout)
{
    __shared__ __align__(16) __bf16 Ks[2][64][128];  // double K-tile, XOR-swz
    __shared__ float rts[96];

    const int tid = threadIdx.x;
    const int w = tid >> 6, lane = tid & 63;
    const int quad = lane >> 4, l16 = lane & 15;
    const int bh = blockIdx.x, qt = blockIdx.y;   // XCD-locality swizzle
    const int b = bh >> 3, h = bh & 7;
    const int n0 = qt * 64;

    if (tid < 95) rts[tid] = rtb[h * 95 + tid] * L2E;

    // K staging map (R3-proven)
    const int ck = (tid & 15) ^ ((tid >> 4) & 7);
    const __bf16* kbase = kx + (size_t)bh * NN * 96 + ck * 8;
    auto STAGE_K = [&](int p, int m0s) {
        #pragma unroll
        for (int i = 0; i < 4; i++) {
            int row = i * 16 + (tid >> 4);
            GLOAD_LDS(kbase + (size_t)(m0s + row) * 96,
                      (char*)Ks + p * 16384 + i * 4096 + tid * 16);
        }
    };
    STAGE_K(0, 0);
    STAGE_K(1, 64);

    // V fragment base (vt4): slot fi -> ((bh*24+mt)*8 + fi)*512 + lane*8
    const __bf16* vwb = vt + (size_t)bh * 24 * 4096 + lane * 8;

    // Q fragments (B-operand): lane l16 holds row n = w*16+l16  (R3 form)
    const int nl = w * 16 + l16;
    const size_t qrow = (size_t)(b * NN + n0 + nl);
    bf16x8 bq_[3];
    bq_[0] = *(const bf16x8*)(qarr + qrow * 512 + h * 64 + quad * 8);
    bq_[1] = *(const bf16x8*)(qarr + qrow * 512 + h * 64 + 32 + quad * 8);
    {   // inline oq: logical k 64..95 -> oq[0..15] then zeros; 0.25*log2e folded
        uint4 a2u = {0u, 0u, 0u, 0u};
        if (quad < 2) {
            float o0 = obs[qrow * 2], o1 = obs[qrow * 2 + 1];
            int f = h * 16 + quad * 8;
            const float sc = 0.25f * L2E;
            __bf16 tmp[8];
            #pragma unroll
            for (int j = 0; j < 8; j++)
                tmp[j] = (__bf16)(sc * (o0 * Woq[f + j] + o1 * Woq[128 + f + j]
                                        + boq[f + j]));
            a2u = *(uint4*)tmp;
        }
        bq_[2] = *(bf16x8*)&a2u;
    }

    // var-bias: row (n&31) fixed per lane; m&31 = (ct&1)*16 + quad*4 + r
    const int rm = (w & 1) * 16 + l16;
    float4 vbA = *(const float4*)(varb + h * 1024 + rm * 32 + quad * 4);
    float4 vbB = *(const float4*)(varb + h * 1024 + rm * 32 + 16 + quad * 4);
    float vA[4] = {vbA.x * L2E, vbA.y * L2E, vbA.z * L2E, vbA.w * L2E};
    float vB[4] = {vbB.x * L2E, vbB.y * L2E, vbB.z * L2E, vbB.w * L2E};
    const int tn = 2 * qt + (w >> 1);

    // ones fragment for the lp MFMA
    union { __bf16 e[4]; short4v s; } one_u;
    #pragma unroll
    for (int j = 0; j < 4; j++) one_u.e[j] = (__bf16)1.0f;
    const short4v ones = one_u.s;

    f32x4 zero4 = {0.f, 0.f, 0.f, 0.f};
    f32x4 o_p[4];                     // [dt]: row=d (quad*4+r within dt), col=n=l16
    f32x4 lpa = zero4;                // all rows equal = lp[n=l16]
    #pragma unroll
    for (int i = 0; i < 4; i++) o_p[i] = zero4;

    auto QK = [&](int p, f32x4* sc) {
        __builtin_amdgcn_s_setprio(1);
        #pragma unroll
        for (int ct = 0; ct < 4; ct++) {
            f32x4 d = zero4;
            int row = ct * 16 + l16;
            #pragma unroll
            for (int ks = 0; ks < 3; ks++) {
                bf16x8 kf = *(const bf16x8*)((const char*)Ks + p * 16384
                                + row * 256 + (((ks * 4 + quad) ^ (row & 7)) * 16));
                d = __builtin_amdgcn_mfma_f32_16x16x32_bf16(kf, bq_[ks], d, 0, 0, 0);
            }
            sc[ct] = d;
        }
        __builtin_amdgcn_s_setprio(0);
    };
    auto SM = [&](const f32x4* sc, int mt, short4v* pf) {
        float tb0 = rts[tn - 2 * mt + 47];
        float tb1 = rts[tn - 2 * mt + 46];
        #pragma unroll
        for (int ct = 0; ct < 4; ct++) {
            float tb = (ct & 2) ? tb1 : tb0;
            const float* vv = (ct & 1) ? vB : vA;
            union { __bf16 e[4]; short4v s; } pk;
            #pragma unroll
            for (int r = 0; r < 4; r++)
                pk.e[r] = (__bf16)exp2f(sc[ct][r] + tb + vv[r]);
            pf[ct] = pk.s;
        }
    };
    auto PV = [&](const short8v* vfr, const short4v* pf) {
        __builtin_amdgcn_s_setprio(1);
        #pragma unroll
        for (int ct = 0; ct < 4; ct++) {
            lpa = __builtin_amdgcn_mfma_f32_16x16x16bf16_1k(ones, pf[ct], lpa, 0, 0, 0);
            #pragma unroll
            for (int dt = 0; dt < 4; dt++) {
                short8v v8 = vfr[ct * 2 + (dt >> 1)];
                short4v va = (dt & 1)
                    ? __builtin_shufflevector(v8, v8, 4, 5, 6, 7)
                    : __builtin_shufflevector(v8, v8, 0, 1, 2, 3);
                o_p[dt] = __builtin_amdgcn_mfma_f32_16x16x16bf16_1k(
                    va, pf[ct], o_p[dt], 0, 0, 0);
            }
        }
        __builtin_amdgcn_s_setprio(0);
    };

    __syncthreads();   // tiles 0,1 staged + rts visible

    for (int i = 0; i < 12; i++) {
        const int mt0 = 2 * i;
        // V fragments for tile mt0 (global->VGPR, consumed at PV0)
        short8v v0[8];
        {
            const __bf16* vp = vwb + (size_t)mt0 * 4096;
            #pragma unroll
            for (int fi = 0; fi < 8; fi++)
                v0[fi] = *(const short8v*)(vp + fi * 512);
        }
        f32x4 sc0[4], sc1[4];
        QK(0, sc0);
        QK(1, sc1);
        __syncthreads();             // all waves done reading Ks pair
        if (i < 11) {
            STAGE_K(0, (mt0 + 2) * 64);
            STAGE_K(1, (mt0 + 3) * 64);
        }
        short4v p0[4];
        SM(sc0, mt0, p0);
        // V fragments for tile mt0+1 (covered by PV0 + SM1)
        short8v v1[8];
        {
            const __bf16* vp = vwb + (size_t)(mt0 + 1) * 4096;
            #pragma unroll
            for (int fi = 0; fi < 8; fi++)
                v1[fi] = *(const short8v*)(vp + fi * 512);
        }
        PV(v0, p0);
        short4v p1[4];
        SM(sc1, mt0 + 1, p1);
        PV(v1, p1);
        __syncthreads();             // staged K pair landed everywhere
    }

    // ---- epilogue: lp complete per lane (col n=l16), direct store ----
    float linv = 1.0f / lpa[0];
    size_t abase = ((size_t)(b * NN) + n0 + nl) * 512 + h * 64 + quad * 4;
    #pragma unroll
    for (int dt = 0; dt < 4; dt++) {
        __bf16 ov[4];
        #pragma unroll
        for (int r = 0; r < 4; r++) ov[r] = (__bf16)(o_p[dt][r] * linv);
        *(uint2*)(aout + abase + dt * 16) = *(uint2*)ov;
    }
}

extern "C" void kernel_launch(void* const* d_in, const int* in_sizes, int n_in,
                              void* d_out, int out_size, void* d_ws, size_t ws_size,
                              hipStream_t stream)
{
    const float* h_   = (const float*)d_in[0];
    const float* obs  = (const float*)d_in[1];
    const float* Wq   = (const float*)d_in[2];
    const float* bq   = (const float*)d_in[3];
    const float* Wk   = (const float*)d_in[4];
    const float* bk   = (const float*)d_in[5];
    const float* Wv   = (const float*)d_in[6];
    const float* bv   = (const float*)d_in[7];
    const float* Wo   = (const float*)d_in[8];
    const float* bo   = (const float*)d_in[9];
    const float* Woq  = (const float*)d_in[10];
    const float* boq  = (const float*)d_in[11];
    const float* Wok  = (const float*)d_in[12];
    const float* bok  = (const float*)d_in[13];
    const float* varb = (const float*)d_in[14];
    const float* rtb  = (const float*)d_in[15];
    float* out = (float*)d_out;

    char* ws = (char*)d_ws;
    __bf16* h_bf    = (__bf16*)ws;                 ws += (size_t)NBN * 512 * 2;
    __bf16* qarr    = (__bf16*)ws;                 ws += (size_t)NBN * 512 * 2;
    __bf16* vt      = (__bf16*)ws;                 ws += (size_t)NBN * 512 * 2;
    __bf16* kx      = (__bf16*)ws;                 ws += ((size_t)32 * NN * 96 + 64) * 2;
    __bf16* attnout = (__bf16*)ws;                 ws += (size_t)NBN * 512 * 2;
    __bf16* WcatT   = (__bf16*)ws;                 ws += (size_t)1536 * 512 * 2;
    __bf16* WoT     = (__bf16*)ws;                 ws += (size_t)512 * 512 * 2;
    float*  biascat = (float*)ws;                  ws += 1536 * 4;

    prep<<<dim3(2176), dim3(256), 0, stream>>>(
        h_, obs, Wq, Wk, Wv, Wo, bq, bk, bv, Wok, bok,
        h_bf, WcatT, WoT, biascat, kx);
    gemm_mfma<128, true><<<dim3(12, 48), dim3(256), 0, stream>>>(
        h_bf, WcatT, biascat, nullptr, qarr, kx, vt);
    attn_mfma<<<dim3(32, 24), dim3(256), 0, stream>>>(qarr, kx, vt, obs, Woq, boq,
                                                      varb, rtb, attnout);
    gemm_mfma<64, false><<<dim3(4, 96), dim3(256), 0, stream>>>(
        attnout, WoT, bo, out, nullptr, nullptr, nullptr);
}